// Round 17
// baseline (99.482 us; speedup 1.0000x reference)
//
#include <hip/hip_runtime.h>
#include <math.h>

// RoPE+SDPA attention. Round 15:
// (1) attn: T15 2-deep software pipeline — QK(t) MFMA overlaps
//     softmax-finish(t-1) VALU, then PV(t-1); 4 LDS buffers, stage distance 2,
//     ONE barrier/iter, counted vmcnt. Fully unrolled (compile-time indices).
// (2) out_gemm: BK=64 (8 steps, half the barriers) + XOR swizzle.
// qkv (R12 best) and convert unchanged.
// B=8 L=1024 H=8 Dh=64 HID=512.

#define BB 8
#define LL 1024
#define HH 8
#define DH 64
#define HID 512

typedef __bf16 bf16x8 __attribute__((ext_vector_type(8)));
typedef float f32x4 __attribute__((ext_vector_type(4)));
typedef float f32x16 __attribute__((ext_vector_type(16)));
typedef unsigned short u16x8 __attribute__((ext_vector_type(8)));
typedef unsigned short u16x4 __attribute__((ext_vector_type(4)));
typedef unsigned u32x4 __attribute__((ext_vector_type(4)));

__device__ inline unsigned short f2bf(float f) {
    union { float f; unsigned u; } v; v.f = f;
    unsigned r = v.u + 0x7fffu + ((v.u >> 16) & 1u);
    return (unsigned short)(r >> 16);
}

__device__ inline float fexp2(float x) {
    float r;
    asm("v_exp_f32 %0, %1" : "=v"(r) : "v"(x));
    return r;
}

#define GLOAD_LDS16(g, l) __builtin_amdgcn_global_load_lds( \
    (const __attribute__((address_space(1))) unsigned int*)(g), \
    (__attribute__((address_space(3))) unsigned int*)(l), 16, 0, 0)

__device__ inline bf16x8 pack8(float e0, float e1, float e2, float e3,
                               float e4, float e5, float e6, float e7) {
    unsigned a0, a1, a2, a3;
    asm("v_cvt_pk_bf16_f32 %0, %1, %2" : "=v"(a0) : "v"(e0), "v"(e1));
    asm("v_cvt_pk_bf16_f32 %0, %1, %2" : "=v"(a1) : "v"(e2), "v"(e3));
    asm("v_cvt_pk_bf16_f32 %0, %1, %2" : "=v"(a2) : "v"(e4), "v"(e5));
    asm("v_cvt_pk_bf16_f32 %0, %1, %2" : "=v"(a3) : "v"(e6), "v"(e7));
    asm("v_permlane32_swap_b32 %0, %1" : "+v"(a0), "+v"(a2));
    asm("v_permlane32_swap_b32 %0, %1" : "+v"(a1), "+v"(a3));
    u32x4 wv; wv[0] = a0; wv[1] = a1; wv[2] = a2; wv[3] = a3;
    return *(bf16x8*)&wv;
}

#define Z16 {0.f,0.f,0.f,0.f,0.f,0.f,0.f,0.f,0.f,0.f,0.f,0.f,0.f,0.f,0.f,0.f}

// ---------------- fp32 -> bf16 convert (x, 4 W's) + RoPE table --------------
__global__ __launch_bounds__(256) void convert_kernel(
    const float* __restrict__ x, const float* __restrict__ Wq,
    const float* __restrict__ Wk, const float* __restrict__ Wv,
    const float* __restrict__ Wo,
    unsigned short* __restrict__ xb, unsigned short* __restrict__ wqb,
    unsigned short* __restrict__ wkb, unsigned short* __restrict__ wvb,
    unsigned short* __restrict__ wob,
    float* __restrict__ cos_t, float* __restrict__ sin_t)
{
    int blk = blockIdx.x;
    if (blk >= 2560) {
        int idx = (blk - 2560) * 256 + threadIdx.x;
        int l = idx >> 5, j = idx & 31;
        float inv = exp2f(-(float)j * (13.287712379549449f / 32.0f));
        float th = (float)l * inv;
        cos_t[idx] = cosf(th);
        sin_t[idx] = sinf(th);
        return;
    }
    const float* s; unsigned short* d; int off;
    if (blk < 2048) { s = x; d = xb; off = blk; }
    else {
        int t = (blk - 2048) >> 7;
        off = (blk - 2048) & 127;
        s = (t == 0) ? Wq : (t == 1) ? Wk : (t == 2) ? Wv : Wo;
        d = (t == 0) ? wqb : (t == 1) ? wkb : (t == 2) ? wvb : wob;
    }
    size_t base = ((size_t)off * 256 + threadIdx.x) * 8;
    float4 a = *(const float4*)(s + base);
    float4 b = *(const float4*)(s + base + 4);
    u16x8 pk;
    pk[0] = f2bf(a.x); pk[1] = f2bf(a.y); pk[2] = f2bf(a.z); pk[3] = f2bf(a.w);
    pk[4] = f2bf(b.x); pk[5] = f2bf(b.y); pk[6] = f2bf(b.z); pk[7] = f2bf(b.w);
    *(u16x8*)(d + base) = pk;
}

// ---------------- QKV projection GEMM: BK=64, swizzled LDS, fused RoPE ------
__global__ __launch_bounds__(256) void qkv_gemm_kernel(
    const unsigned short* __restrict__ xb, const unsigned short* __restrict__ Wqb,
    const unsigned short* __restrict__ Wkb, const unsigned short* __restrict__ Wvb,
    const float* __restrict__ cos_t, const float* __restrict__ sin_t,
    unsigned short* __restrict__ Qb, unsigned short* __restrict__ Kb,
    unsigned short* __restrict__ Vt)
{
    __shared__ unsigned short As[128 * 64];
    __shared__ unsigned short Bs[128 * 64];

    const int mt = blockIdx.x;
    const int nt = blockIdx.y;
    const int mbase = mt * 128;
    const int mat = nt >> 2;
    const unsigned short* W = (mat == 0) ? Wqb : ((mat == 1) ? Wkb : Wvb);
    const int nW = (nt & 3) * 128;

    const int tid = threadIdx.x;
    const int w = tid >> 6, lane = tid & 63;
    const int wr = w >> 1, wc = w & 1;
    const int l15 = lane & 15, koff = (lane >> 4) * 8;

    const int srow = w * 8 + (lane >> 3);
    const int ssw = ((lane & 7) * 8) ^ (((lane >> 3) & 7) * 8);

    const int rsw = (l15 & 7) * 8;
    const int ck0 = (koff +  0) ^ rsw;
    const int ck1 = (koff + 32) ^ rsw;

    f32x4 acc[4][4];
    #pragma unroll
    for (int i = 0; i < 4; ++i)
        #pragma unroll
        for (int j = 0; j < 4; ++j) acc[i][j] = (f32x4){0.f, 0.f, 0.f, 0.f};

    for (int kc = 0; kc < 512; kc += 64) {
        __syncthreads();
        #pragma unroll
        for (int j = 0; j < 4; ++j) {
            int row = j * 32 + srow;
            GLOAD_LDS16(xb + (size_t)(mbase + row) * 512 + kc + ssw,
                        As + j * 2048 + w * 512);
            GLOAD_LDS16(W + (size_t)(nW + row) * 512 + kc + ssw,
                        Bs + j * 2048 + w * 512);
        }
        __syncthreads();

        bf16x8 af[4][2], bf[4][2];
        #pragma unroll
        for (int mi = 0; mi < 4; ++mi) {
            int r = (wr * 64 + mi * 16 + l15) * 64;
            af[mi][0] = *(const bf16x8*)&As[r + ck0];
            af[mi][1] = *(const bf16x8*)&As[r + ck1];
        }
        #pragma unroll
        for (int ni = 0; ni < 4; ++ni) {
            int r = (wc * 64 + ni * 16 + l15) * 64;
            bf[ni][0] = *(const bf16x8*)&Bs[r + ck0];
            bf[ni][1] = *(const bf16x8*)&Bs[r + ck1];
        }
        #pragma unroll
        for (int mi = 0; mi < 4; ++mi)
            #pragma unroll
            for (int ni = 0; ni < 4; ++ni) {
                acc[mi][ni] = __builtin_amdgcn_mfma_f32_16x16x32_bf16(
                    af[mi][0], bf[ni][0], acc[mi][ni], 0, 0, 0);
                acc[mi][ni] = __builtin_amdgcn_mfma_f32_16x16x32_bf16(
                    af[mi][1], bf[ni][1], acc[mi][ni], 0, 0, 0);
            }
    }

    const int h = (nt & 3) * 2 + wc;
    if (mat < 2) {
        unsigned short* D = (mat == 0) ? Qb : Kb;
        const float sc = (mat == 0) ? 0.18033688011112042f /*0.125*log2(e)*/ : 1.0f;
        #pragma unroll
        for (int mi = 0; mi < 4; ++mi) {
            int m = mbase + wr * 64 + mi * 16 + (lane >> 4) * 4;
            int b = m >> 10, l0 = m & 1023;
            #pragma unroll
            for (int r = 0; r < 4; ++r) {
                int l = l0 + r;
                float c0 = cos_t[l * 32 + l15],      s0 = sin_t[l * 32 + l15];
                float c1 = cos_t[l * 32 + 16 + l15], s1 = sin_t[l * 32 + 16 + l15];
                float a0 = acc[mi][0][r], a1 = acc[mi][1][r];
                float a2 = acc[mi][2][r], a3 = acc[mi][3][r];
                float o0 = (a0 * c0 - a2 * s0) * sc;
                float o1 = (a1 * c1 - a3 * s1) * sc;
                float o2 = (a2 * c0 + a0 * s0) * sc;
                float o3 = (a3 * c1 + a1 * s1) * sc;
                size_t rowbase = ((size_t)(b * HH + h) * LL + l) * 64;
                D[rowbase +  0 + l15] = f2bf(o0);
                D[rowbase + 16 + l15] = f2bf(o1);
                D[rowbase + 32 + l15] = f2bf(o2);
                D[rowbase + 48 + l15] = f2bf(o3);
            }
        }
    } else {
        #pragma unroll
        for (int mi = 0; mi < 4; ++mi) {
            int m = mbase + wr * 64 + mi * 16 + (lane >> 4) * 4;
            int b = m >> 10, l0 = m & 1023;
            #pragma unroll
            for (int ni = 0; ni < 4; ++ni) {
                int d = ni * 16 + l15;
                u16x4 pk;
                #pragma unroll
                for (int r = 0; r < 4; ++r) pk[r] = f2bf(acc[mi][ni][r]);
                *(u16x4*)(Vt + ((size_t)(b * HH + h) * 64 + d) * LL + l0) = pk;
            }
        }
    }
}

// ---------------- Flash attention: T15 2-deep pipeline ----------------------
// Per iter t: vmcnt(4)+barrier -> stage(t+2) -> QK(t) [MFMA] ->
// finish(t-1) [VALU, overlaps QK] -> PV(t-1) [MFMA]. Fully unrolled.
__global__ __launch_bounds__(256) void attn_kernel(
    const unsigned short* __restrict__ Q, const unsigned short* __restrict__ K,
    const unsigned short* __restrict__ Vt, unsigned short* __restrict__ O)
{
    __shared__ unsigned short Ks[4][64 * 64];    // 32 KB
    __shared__ unsigned short Vs[4][64 * 64];    // 32 KB

    const int wgid = blockIdx.x;    // 0..511
    const int xcd = wgid & 7;
    const int j = wgid >> 3;        // 0..63
    const int bh = xcd * 8 + (j >> 3);
    const int qt = j & 7;
    const int b = bh >> 3, h = bh & 7;
    const int tid = threadIdx.x;
    const int w = tid >> 6;
    const int lane = tid & 63;
    const int l31 = lane & 31;
    const int hi5 = lane >> 5;

    const unsigned short* Qp = Q + (size_t)bh * LL * 64;
    const unsigned short* Kp = K + (size_t)bh * LL * 64;
    const unsigned short* Vp = Vt + (size_t)bh * 64 * LL;

    const int sr0 = w * 8 + (lane >> 3);
    const int sr1 = 32 + w * 8 + (lane >> 3);
    const int scsw = ((lane & 7) * 8) ^ (((lane >> 3) & 7) * 8);
    const int sd0 = w * 512;
    const int sd1 = 2048 + w * 512;

    const int q0 = qt * 128 + w * 32;

    bf16x8 qf0 = *(const bf16x8*)(Qp + (size_t)(q0 + l31) * 64 +  0 + hi5 * 8);
    bf16x8 qf1 = *(const bf16x8*)(Qp + (size_t)(q0 + l31) * 64 + 16 + hi5 * 8);
    bf16x8 qf2 = *(const bf16x8*)(Qp + (size_t)(q0 + l31) * 64 + 32 + hi5 * 8);
    bf16x8 qf3 = *(const bf16x8*)(Qp + (size_t)(q0 + l31) * 64 + 48 + hi5 * 8);

    const int swz = (l31 & 7) * 8;
    const int co0 = ( 0 + hi5 * 8) ^ swz;
    const int co1 = (16 + hi5 * 8) ^ swz;
    const int co2 = (32 + hi5 * 8) ^ swz;
    const int co3 = (48 + hi5 * 8) ^ swz;
    const int rA = l31 * 64;
    const int rB = (32 + l31) * 64;

    float lsum = 0.f;
    f32x16 opv0 = Z16, opv1 = Z16;
    f32x16 s0p = Z16, s1p = Z16;     // prev-tile S state

#define STAGE(T) do { \
        const int _nb = (T) & 3; const int _kb = (T) * 64; \
        GLOAD_LDS16(Kp + (size_t)(_kb + sr0) * 64 + scsw, &Ks[_nb][sd0]); \
        GLOAD_LDS16(Kp + (size_t)(_kb + sr1) * 64 + scsw, &Ks[_nb][sd1]); \
        GLOAD_LDS16(Vp + (size_t)sr0 * LL + _kb + scsw, &Vs[_nb][sd0]);   \
        GLOAD_LDS16(Vp + (size_t)sr1 * LL + _kb + scsw, &Vs[_nb][sd1]);   \
    } while (0)

#define QK(T, S0, S1) do { \
        const int _c = (T) & 3; bf16x8 _kA, _kB; \
        _kA = *(const bf16x8*)&Ks[_c][rA + co0]; _kB = *(const bf16x8*)&Ks[_c][rB + co0]; \
        S0 = __builtin_amdgcn_mfma_f32_32x32x16_bf16(_kA, qf0, S0, 0, 0, 0); \
        S1 = __builtin_amdgcn_mfma_f32_32x32x16_bf16(_kB, qf0, S1, 0, 0, 0); \
        _kA = *(const bf16x8*)&Ks[_c][rA + co1]; _kB = *(const bf16x8*)&Ks[_c][rB + co1]; \
        S0 = __builtin_amdgcn_mfma_f32_32x32x16_bf16(_kA, qf1, S0, 0, 0, 0); \
        S1 = __builtin_amdgcn_mfma_f32_32x32x16_bf16(_kB, qf1, S1, 0, 0, 0); \
        _kA = *(const bf16x8*)&Ks[_c][rA + co2]; _kB = *(const bf16x8*)&Ks[_c][rB + co2]; \
        S0 = __builtin_amdgcn_mfma_f32_32x32x16_bf16(_kA, qf2, S0, 0, 0, 0); \
        S1 = __builtin_amdgcn_mfma_f32_32x32x16_bf16(_kB, qf2, S1, 0, 0, 0); \
        _kA = *(const bf16x8*)&Ks[_c][rA + co3]; _kB = *(const bf16x8*)&Ks[_c][rB + co3]; \
        S0 = __builtin_amdgcn_mfma_f32_32x32x16_bf16(_kA, qf3, S0, 0, 0, 0); \
        S1 = __builtin_amdgcn_mfma_f32_32x32x16_bf16(_kB, qf3, S1, 0, 0, 0); \
    } while (0)

#define FINISH_PV(T) do { \
        float e[16], f[16]; \
        _Pragma("unroll") for (int i = 0; i < 16; ++i) e[i] = fexp2(s0p[i]); \
        _Pragma("unroll") for (int i = 0; i < 16; ++i) f[i] = fexp2(s1p[i]); \
        lsum += (((e[0]+e[1])+(e[2]+e[3])) + ((e[4]+e[5])+(e[6]+e[7]))) \
              + (((e[8]+e[9])+(e[10]+e[11])) + ((e[12]+e[13])+(e[14]+e[15]))); \
        lsum += (((f[0]+f[1])+(f[2]+f[3])) + ((f[4]+f[5])+(f[6]+f[7]))) \
              + (((f[8]+f[9])+(f[10]+f[11])) + ((f[12]+f[13])+(f[14]+f[15]))); \
        bf16x8 pf0 = pack8(e[0], e[1], e[2], e[3], e[4], e[5], e[6], e[7]); \
        bf16x8 pf1 = pack8(e[8], e[9], e[10], e[11], e[12], e[13], e[14], e[15]); \
        bf16x8 pf2 = pack8(f[0], f[1], f[2], f[3], f[4], f[5], f[6], f[7]); \
        bf16x8 pf3 = pack8(f[8], f[9], f[10], f[11], f[12], f[13], f[14], f[15]); \
        const int _c = (T) & 3; bf16x8 _vA, _vB; \
        _vA = *(const bf16x8*)&Vs[_c][rA + co0]; _vB = *(const bf16x8*)&Vs[_c][rB + co0]; \
        opv0 = __builtin_amdgcn_mfma_f32_32x32x16_bf16(_vA, pf0, opv0, 0, 0, 0); \
        opv1 = __builtin_amdgcn_mfma_f32_32x32x16_bf16(_vB, pf0, opv1, 0, 0, 0); \
        _vA = *(const bf16x8*)&Vs[_c][rA + co1]; _vB = *(const bf16x8*)&Vs[_c][rB + co1]; \
        opv0 = __builtin_amdgcn_mfma_f32_32x32x16_bf16(_vA, pf1, opv0, 0, 0, 0); \
        opv1 = __builtin_amdgcn_mfma_f32_32x32x16_bf16(_vB, pf1, opv1, 0, 0, 0); \
        _vA = *(const bf16x8*)&Vs[_c][rA + co2]; _vB = *(const bf16x8*)&Vs[_c][rB + co2]; \
        opv0 = __builtin_amdgcn_mfma_f32_32x32x16_bf16(_vA, pf2, opv0, 0, 0, 0); \
        opv1 = __builtin_amdgcn_mfma_f32_32x32x16_bf16(_vB, pf2, opv1, 0, 0, 0); \
        _vA = *(const bf16x8*)&Vs[_c][rA + co3]; _vB = *(const bf16x8*)&Vs[_c][rB + co3]; \
        opv0 = __builtin_amdgcn_mfma_f32_32x32x16_bf16(_vA, pf3, opv0, 0, 0, 0); \
        opv1 = __builtin_amdgcn_mfma_f32_32x32x16_bf16(_vB, pf3, opv1, 0, 0, 0); \
    } while (0)

    // prologue: stage tiles 0,1,2; QK(0)
    STAGE(0); STAGE(1); STAGE(2);
    asm volatile("s_waitcnt vmcnt(8)" ::: "memory");   // tile 0 landed
    __builtin_amdgcn_s_barrier();
    __builtin_amdgcn_s_setprio(1);
    QK(0, s0p, s1p);
    __builtin_amdgcn_s_setprio(0);

    #pragma unroll
    for (int t = 1; t < 16; ++t) {
        if (t <= 14) {
            asm volatile("s_waitcnt vmcnt(4)" ::: "memory");   // tile t landed
        } else {
            asm volatile("s_waitcnt vmcnt(0)" ::: "memory");
        }
        __builtin_amdgcn_s_barrier();   // tile t visible; prev-tile reads all done
        if (t <= 13) STAGE(t + 2);

        f32x16 s0c = Z16, s1c = Z16;
        __builtin_amdgcn_s_setprio(1);
        QK(t, s0c, s1c);
        __builtin_amdgcn_s_setprio(0);

        FINISH_PV(t - 1);               // VALU finish(t-1) overlaps QK(t) MFMA

        s0p = s0c; s1p = s1c;           // SSA-renamed under full unroll
        asm volatile("" ::: "memory");
    }

    // epilogue: finish + PV for tile 15
    FINISH_PV(15);

    lsum += __shfl_xor(lsum, 32);

    const float inv = 1.f / lsum;
    unsigned short* ob = O + (size_t)(b * LL + q0 + l31) * HID + h * 64;
    #pragma unroll
    for (int rg = 0; rg < 4; ++rg) {
        u16x4 pkA, pkB;
        #pragma unroll
        for (int rr = 0; rr < 4; ++rr) {
            pkA[rr] = f2bf(opv0[rg * 4 + rr] * inv);
            pkB[rr] = f2bf(opv1[rg * 4 + rr] * inv);
        }
        *(u16x4*)(ob + rg * 8 + hi5 * 4)      = pkA;
        *(u16x4*)(ob + 32 + rg * 8 + hi5 * 4) = pkB;
    }
#undef STAGE
#undef QK
#undef FINISH_PV
}

// ---------------- Output GEMM: 128x64 tile, BK=64, swizzled ----------------
__global__ __launch_bounds__(256) void out_gemm_kernel(
    const unsigned short* __restrict__ AOb, const unsigned short* __restrict__ Wob,
    float* __restrict__ out)
{
    __shared__ unsigned short As[128 * 64];   // 16 KB
    __shared__ unsigned short Bs[64 * 64];    // 8 KB

    const int mt = blockIdx.x;          // 0..63
    const int nt = blockIdx.y;          // 0..7
    const int mbase = mt * 128;
    const int nbase = nt * 64;

    const int tid = threadIdx.x;
    const int w = tid >> 6, lane = tid & 63;
    const int wr = w >> 1, wc = w & 1;
    const int l15 = lane & 15, koff = (lane >> 4) * 8;

    const int srow = w * 8 + (lane >> 3);
    const int ssw = ((lane & 7) * 8) ^ (((lane >> 3) & 7) * 8);
    const int rsw = (l15 & 7) * 8;
    const int ck0 = (koff +  0) ^ rsw;
    const int ck1 = (koff + 32) ^ rsw;

    f32x4 acc[4][2];
    #pragma unroll
    for (int i = 0; i < 4; ++i)
        #pragma unroll
        for (int j = 0; j < 2; ++j) acc[i][j] = (f32x4){0.f, 0.f, 0.f, 0.f};

    for (int kc = 0; kc < 512; kc += 64) {
        __syncthreads();
        #pragma unroll
        for (int j = 0; j < 4; ++j) {
            int row = j * 32 + srow;
            GLOAD_LDS16(AOb + (size_t)(mbase + row) * 512 + kc + ssw,
                        As + j * 2048 + w * 512);
        }
        #pragma unroll
        for (int c = 0; c < 2; ++c) {
            int row = c * 32 + srow;
            GLOAD_LDS16(Wob + (size_t)(nbase + row) * 512 + kc + ssw,
                        Bs + c * 2048 + w * 512);
        }
        __syncthreads();

        bf16x8 af[4][2], bf[2][2];
        #pragma unroll
        for (int mi = 0; mi < 4; ++mi) {
            int r = (wr * 64 + mi * 16 + l15) * 64;
            af[mi][0] = *(const bf16x8*)&As[r + ck0];
            af[mi][1] = *(const bf16x8*)&As[r + ck1];
        }
        #pragma unroll
        for (int ni = 0; ni < 2; ++ni) {
            int r = (wc * 32 + ni * 16 + l15) * 64;
            bf[ni][0] = *(const bf16x8*)&Bs[r + ck0];
            bf[ni][1] = *(const bf16x8*)&Bs[r + ck1];
        }
        #pragma unroll
        for (int mi = 0; mi < 4; ++mi)
            #pragma unroll
            for (int ni = 0; ni < 2; ++ni) {
                acc[mi][ni] = __builtin_amdgcn_mfma_f32_16x16x32_bf16(
                    af[mi][0], bf[ni][0], acc[mi][ni], 0, 0, 0);
                acc[mi][ni] = __builtin_amdgcn_mfma_f32_16x16x32_bf16(
                    af[mi][1], bf[ni][1], acc[mi][ni], 0, 0, 0);
            }
    }

    #pragma unroll
    for (int mi = 0; mi < 4; ++mi) {
        int m = mbase + wr * 64 + mi * 16 + (lane >> 4) * 4;
        #pragma unroll
        for (int r = 0; r < 4; ++r) {
            size_t rowbase = (size_t)(m + r) * 512 + nbase + wc * 32;
            #pragma unroll
            for (int ni = 0; ni < 2; ++ni)
                out[rowbase + ni * 16 + l15] = acc[mi][ni][r];
        }
    }
}

extern "C" void kernel_launch(void* const* d_in, const int* in_sizes, int n_in,
                              void* d_out, int out_size, void* d_ws, size_t ws_size,
                              hipStream_t stream) {
    const float* x  = (const float*)d_in[0];
    const float* Wq = (const float*)d_in[1];
    const float* Wk = (const float*)d_in[2];
    const float* Wv = (const float*)d_in[3];
    const float* Wo = (const float*)d_in[4];
    float* out = (float*)d_out;

    const size_t tblN = (size_t)LL * 32;
    const size_t qkvN = (size_t)BB * HH * LL * 64;
    const size_t wN   = (size_t)HID * HID;

    float* cos_t = (float*)d_ws;
    float* sin_t = cos_t + tblN;
    unsigned short* Qb  = (unsigned short*)(sin_t + tblN);
    unsigned short* Kb  = Qb + qkvN;
    unsigned short* Vt  = Kb + qkvN;
    unsigned short* xb  = Vt + qkvN;
    unsigned short* Wqb = xb + qkvN;
    unsigned short* Wkb = Wqb + wN;
    unsigned short* Wvb = Wkb + wN;
    unsigned short* Wob = Wvb + wN;
    unsigned short* AOb = Wob + wN;

    hipLaunchKernelGGL(convert_kernel, dim3(2048 + 512 + 128), dim3(256), 0, stream,
                       x, Wq, Wk, Wv, Wo, xb, Wqb, Wkb, Wvb, Wob, cos_t, sin_t);
    hipLaunchKernelGGL(qkv_gemm_kernel, dim3(64, 12), dim3(256), 0, stream,
                       xb, Wqb, Wkb, Wvb, cos_t, sin_t, Qb, Kb, Vt);
    hipLaunchKernelGGL(attn_kernel, dim3(512), dim3(256), 0, stream,
                       Qb, Kb, Vt, AOb);
    hipLaunchKernelGGL(out_gemm_kernel, dim3(64, 8), dim3(256), 0, stream,
                       AOb, Wob, out);
}

// Round 18
// 72.628 us; speedup vs baseline: 1.3698x; 1.3698x over previous
//
#include <hip/hip_runtime.h>
#include <math.h>

// RoPE+SDPA attention. Round 16: REVERT attn to R12 (best, 73.8µs total) —
// R15's 2-state T15 pipeline spilled (VGPR 256, 61MB scratch writes).
// Single retained delta vs R12: out_gemm at BK=64 + XOR swizzle (half the
// barriers, conflict-free reads). qkv/convert unchanged from R12.
// B=8 L=1024 H=8 Dh=64 HID=512.

#define BB 8
#define LL 1024
#define HH 8
#define DH 64
#define HID 512

typedef __bf16 bf16x8 __attribute__((ext_vector_type(8)));
typedef float f32x4 __attribute__((ext_vector_type(4)));
typedef float f32x16 __attribute__((ext_vector_type(16)));
typedef unsigned short u16x8 __attribute__((ext_vector_type(8)));
typedef unsigned short u16x4 __attribute__((ext_vector_type(4)));
typedef unsigned u32x4 __attribute__((ext_vector_type(4)));

__device__ inline unsigned short f2bf(float f) {
    union { float f; unsigned u; } v; v.f = f;
    unsigned r = v.u + 0x7fffu + ((v.u >> 16) & 1u);
    return (unsigned short)(r >> 16);
}

// single-instruction exp2 — valid for |x| well inside normal range
__device__ inline float fexp2(float x) {
    float r;
    asm("v_exp_f32 %0, %1" : "=v"(r) : "v"(x));
    return r;
}

#define GLOAD_LDS16(g, l) __builtin_amdgcn_global_load_lds( \
    (const __attribute__((address_space(1))) unsigned int*)(g), \
    (__attribute__((address_space(3))) unsigned int*)(l), 16, 0, 0)

// T12 pack: 8 f32 C-layout P values -> one PV B-frag (cvt_pk + permlane32_swap)
__device__ inline bf16x8 pack8(float e0, float e1, float e2, float e3,
                               float e4, float e5, float e6, float e7) {
    unsigned a0, a1, a2, a3;
    asm("v_cvt_pk_bf16_f32 %0, %1, %2" : "=v"(a0) : "v"(e0), "v"(e1));
    asm("v_cvt_pk_bf16_f32 %0, %1, %2" : "=v"(a1) : "v"(e2), "v"(e3));
    asm("v_cvt_pk_bf16_f32 %0, %1, %2" : "=v"(a2) : "v"(e4), "v"(e5));
    asm("v_cvt_pk_bf16_f32 %0, %1, %2" : "=v"(a3) : "v"(e6), "v"(e7));
    asm("v_permlane32_swap_b32 %0, %1" : "+v"(a0), "+v"(a2));
    asm("v_permlane32_swap_b32 %0, %1" : "+v"(a1), "+v"(a3));
    u32x4 wv; wv[0] = a0; wv[1] = a1; wv[2] = a2; wv[3] = a3;
    return *(bf16x8*)&wv;
}

#define Z16 {0.f,0.f,0.f,0.f,0.f,0.f,0.f,0.f,0.f,0.f,0.f,0.f,0.f,0.f,0.f,0.f}

// ---------------- fp32 -> bf16 convert (x, 4 W's) + RoPE table --------------
__global__ __launch_bounds__(256) void convert_kernel(
    const float* __restrict__ x, const float* __restrict__ Wq,
    const float* __restrict__ Wk, const float* __restrict__ Wv,
    const float* __restrict__ Wo,
    unsigned short* __restrict__ xb, unsigned short* __restrict__ wqb,
    unsigned short* __restrict__ wkb, unsigned short* __restrict__ wvb,
    unsigned short* __restrict__ wob,
    float* __restrict__ cos_t, float* __restrict__ sin_t)
{
    int blk = blockIdx.x;
    if (blk >= 2560) {
        int idx = (blk - 2560) * 256 + threadIdx.x;
        int l = idx >> 5, j = idx & 31;
        float inv = exp2f(-(float)j * (13.287712379549449f / 32.0f));
        float th = (float)l * inv;
        cos_t[idx] = cosf(th);
        sin_t[idx] = sinf(th);
        return;
    }
    const float* s; unsigned short* d; int off;
    if (blk < 2048) { s = x; d = xb; off = blk; }
    else {
        int t = (blk - 2048) >> 7;
        off = (blk - 2048) & 127;
        s = (t == 0) ? Wq : (t == 1) ? Wk : (t == 2) ? Wv : Wo;
        d = (t == 0) ? wqb : (t == 1) ? wkb : (t == 2) ? wvb : wob;
    }
    size_t base = ((size_t)off * 256 + threadIdx.x) * 8;
    float4 a = *(const float4*)(s + base);
    float4 b = *(const float4*)(s + base + 4);
    u16x8 pk;
    pk[0] = f2bf(a.x); pk[1] = f2bf(a.y); pk[2] = f2bf(a.z); pk[3] = f2bf(a.w);
    pk[4] = f2bf(b.x); pk[5] = f2bf(b.y); pk[6] = f2bf(b.z); pk[7] = f2bf(b.w);
    *(u16x8*)(d + base) = pk;
}

// ---------------- QKV projection GEMM: BK=64, swizzled LDS, fused RoPE ------
__global__ __launch_bounds__(256) void qkv_gemm_kernel(
    const unsigned short* __restrict__ xb, const unsigned short* __restrict__ Wqb,
    const unsigned short* __restrict__ Wkb, const unsigned short* __restrict__ Wvb,
    const float* __restrict__ cos_t, const float* __restrict__ sin_t,
    unsigned short* __restrict__ Qb, unsigned short* __restrict__ Kb,
    unsigned short* __restrict__ Vt)
{
    __shared__ unsigned short As[128 * 64];
    __shared__ unsigned short Bs[128 * 64];

    const int mt = blockIdx.x;
    const int nt = blockIdx.y;
    const int mbase = mt * 128;
    const int mat = nt >> 2;
    const unsigned short* W = (mat == 0) ? Wqb : ((mat == 1) ? Wkb : Wvb);
    const int nW = (nt & 3) * 128;

    const int tid = threadIdx.x;
    const int w = tid >> 6, lane = tid & 63;
    const int wr = w >> 1, wc = w & 1;
    const int l15 = lane & 15, koff = (lane >> 4) * 8;

    const int srow = w * 8 + (lane >> 3);
    const int ssw = ((lane & 7) * 8) ^ (((lane >> 3) & 7) * 8);

    const int rsw = (l15 & 7) * 8;
    const int ck0 = (koff +  0) ^ rsw;
    const int ck1 = (koff + 32) ^ rsw;

    f32x4 acc[4][4];
    #pragma unroll
    for (int i = 0; i < 4; ++i)
        #pragma unroll
        for (int j = 0; j < 4; ++j) acc[i][j] = (f32x4){0.f, 0.f, 0.f, 0.f};

    for (int kc = 0; kc < 512; kc += 64) {
        __syncthreads();
        #pragma unroll
        for (int j = 0; j < 4; ++j) {
            int row = j * 32 + srow;
            GLOAD_LDS16(xb + (size_t)(mbase + row) * 512 + kc + ssw,
                        As + j * 2048 + w * 512);
            GLOAD_LDS16(W + (size_t)(nW + row) * 512 + kc + ssw,
                        Bs + j * 2048 + w * 512);
        }
        __syncthreads();

        bf16x8 af[4][2], bf[4][2];
        #pragma unroll
        for (int mi = 0; mi < 4; ++mi) {
            int r = (wr * 64 + mi * 16 + l15) * 64;
            af[mi][0] = *(const bf16x8*)&As[r + ck0];
            af[mi][1] = *(const bf16x8*)&As[r + ck1];
        }
        #pragma unroll
        for (int ni = 0; ni < 4; ++ni) {
            int r = (wc * 64 + ni * 16 + l15) * 64;
            bf[ni][0] = *(const bf16x8*)&Bs[r + ck0];
            bf[ni][1] = *(const bf16x8*)&Bs[r + ck1];
        }
        #pragma unroll
        for (int mi = 0; mi < 4; ++mi)
            #pragma unroll
            for (int ni = 0; ni < 4; ++ni) {
                acc[mi][ni] = __builtin_amdgcn_mfma_f32_16x16x32_bf16(
                    af[mi][0], bf[ni][0], acc[mi][ni], 0, 0, 0);
                acc[mi][ni] = __builtin_amdgcn_mfma_f32_16x16x32_bf16(
                    af[mi][1], bf[ni][1], acc[mi][ni], 0, 0, 0);
            }
    }

    const int h = (nt & 3) * 2 + wc;
    if (mat < 2) {
        unsigned short* D = (mat == 0) ? Qb : Kb;
        const float sc = (mat == 0) ? 0.18033688011112042f /*0.125*log2(e)*/ : 1.0f;
        #pragma unroll
        for (int mi = 0; mi < 4; ++mi) {
            int m = mbase + wr * 64 + mi * 16 + (lane >> 4) * 4;
            int b = m >> 10, l0 = m & 1023;
            #pragma unroll
            for (int r = 0; r < 4; ++r) {
                int l = l0 + r;
                float c0 = cos_t[l * 32 + l15],      s0 = sin_t[l * 32 + l15];
                float c1 = cos_t[l * 32 + 16 + l15], s1 = sin_t[l * 32 + 16 + l15];
                float a0 = acc[mi][0][r], a1 = acc[mi][1][r];
                float a2 = acc[mi][2][r], a3 = acc[mi][3][r];
                float o0 = (a0 * c0 - a2 * s0) * sc;
                float o1 = (a1 * c1 - a3 * s1) * sc;
                float o2 = (a2 * c0 + a0 * s0) * sc;
                float o3 = (a3 * c1 + a1 * s1) * sc;
                size_t rowbase = ((size_t)(b * HH + h) * LL + l) * 64;
                D[rowbase +  0 + l15] = f2bf(o0);
                D[rowbase + 16 + l15] = f2bf(o1);
                D[rowbase + 32 + l15] = f2bf(o2);
                D[rowbase + 48 + l15] = f2bf(o3);
            }
        }
    } else {
        #pragma unroll
        for (int mi = 0; mi < 4; ++mi) {
            int m = mbase + wr * 64 + mi * 16 + (lane >> 4) * 4;
            int b = m >> 10, l0 = m & 1023;
            #pragma unroll
            for (int ni = 0; ni < 4; ++ni) {
                int d = ni * 16 + l15;
                u16x4 pk;
                #pragma unroll
                for (int r = 0; r < 4; ++r) pk[r] = f2bf(acc[mi][ni][r]);
                *(u16x4*)(Vt + ((size_t)(b * HH + h) * 64 + d) * LL + l0) = pk;
            }
        }
    }
}

// ---------------- Flash attention: R12 structure (proven best) --------------
__global__ __launch_bounds__(256) void attn_kernel(
    const unsigned short* __restrict__ Q, const unsigned short* __restrict__ K,
    const unsigned short* __restrict__ Vt, unsigned short* __restrict__ O)
{
    __shared__ unsigned short Ks[2][64 * 64];    // 16 KB
    __shared__ unsigned short Vs[2][64 * 64];    // 16 KB

    const int wgid = blockIdx.x;    // 0..511
    const int xcd = wgid & 7;
    const int j = wgid >> 3;        // 0..63
    const int bh = xcd * 8 + (j >> 3);
    const int qt = j & 7;
    const int b = bh >> 3, h = bh & 7;
    const int tid = threadIdx.x;
    const int w = tid >> 6;         // 0..3
    const int lane = tid & 63;
    const int l31 = lane & 31;
    const int hi5 = lane >> 5;

    const unsigned short* Qp = Q + (size_t)bh * LL * 64;
    const unsigned short* Kp = K + (size_t)bh * LL * 64;
    const unsigned short* Vp = Vt + (size_t)bh * 64 * LL;

    const int sr0 = w * 8 + (lane >> 3);
    const int sr1 = 32 + w * 8 + (lane >> 3);
    const int scsw = ((lane & 7) * 8) ^ (((lane >> 3) & 7) * 8);
    const int sd0 = w * 512;
    const int sd1 = 2048 + w * 512;

    const int q0 = qt * 128 + w * 32;

    bf16x8 qf0 = *(const bf16x8*)(Qp + (size_t)(q0 + l31) * 64 +  0 + hi5 * 8);
    bf16x8 qf1 = *(const bf16x8*)(Qp + (size_t)(q0 + l31) * 64 + 16 + hi5 * 8);
    bf16x8 qf2 = *(const bf16x8*)(Qp + (size_t)(q0 + l31) * 64 + 32 + hi5 * 8);
    bf16x8 qf3 = *(const bf16x8*)(Qp + (size_t)(q0 + l31) * 64 + 48 + hi5 * 8);

    const int swz = (l31 & 7) * 8;
    const int co0 = ( 0 + hi5 * 8) ^ swz;
    const int co1 = (16 + hi5 * 8) ^ swz;
    const int co2 = (32 + hi5 * 8) ^ swz;
    const int co3 = (48 + hi5 * 8) ^ swz;
    const int rA = l31 * 64;
    const int rB = (32 + l31) * 64;

    float lsum = 0.f;
    f32x16 opv0 = Z16, opv1 = Z16;

    GLOAD_LDS16(Kp + (size_t)sr0 * 64 + scsw, &Ks[0][sd0]);
    GLOAD_LDS16(Kp + (size_t)sr1 * 64 + scsw, &Ks[0][sd1]);
    GLOAD_LDS16(Vp + (size_t)sr0 * LL + scsw, &Vs[0][sd0]);
    GLOAD_LDS16(Vp + (size_t)sr1 * LL + scsw, &Vs[0][sd1]);
    __syncthreads();

    #pragma unroll 2
    for (int kt = 0; kt < 16; ++kt) {
        const int cur = kt & 1, nxt = cur ^ 1;
        const int kbase = kt * 64;

        if (kt < 15) {
            GLOAD_LDS16(Kp + (size_t)(kbase + 64 + sr0) * 64 + scsw, &Ks[nxt][sd0]);
            GLOAD_LDS16(Kp + (size_t)(kbase + 64 + sr1) * 64 + scsw, &Ks[nxt][sd1]);
            GLOAD_LDS16(Vp + (size_t)sr0 * LL + kbase + 64 + scsw, &Vs[nxt][sd0]);
            GLOAD_LDS16(Vp + (size_t)sr1 * LL + kbase + 64 + scsw, &Vs[nxt][sd1]);
            asm volatile("s_waitcnt vmcnt(4)" ::: "memory");
        } else {
            asm volatile("s_waitcnt vmcnt(0)" ::: "memory");
        }
        __builtin_amdgcn_s_barrier();

        f32x16 s0 = Z16, s1 = Z16;
        __builtin_amdgcn_s_setprio(1);
        {
            bf16x8 kA, kB;
            kA = *(const bf16x8*)&Ks[cur][rA + co0];
            kB = *(const bf16x8*)&Ks[cur][rB + co0];
            s0 = __builtin_amdgcn_mfma_f32_32x32x16_bf16(kA, qf0, s0, 0, 0, 0);
            s1 = __builtin_amdgcn_mfma_f32_32x32x16_bf16(kB, qf0, s1, 0, 0, 0);
            kA = *(const bf16x8*)&Ks[cur][rA + co1];
            kB = *(const bf16x8*)&Ks[cur][rB + co1];
            s0 = __builtin_amdgcn_mfma_f32_32x32x16_bf16(kA, qf1, s0, 0, 0, 0);
            s1 = __builtin_amdgcn_mfma_f32_32x32x16_bf16(kB, qf1, s1, 0, 0, 0);
            kA = *(const bf16x8*)&Ks[cur][rA + co2];
            kB = *(const bf16x8*)&Ks[cur][rB + co2];
            s0 = __builtin_amdgcn_mfma_f32_32x32x16_bf16(kA, qf2, s0, 0, 0, 0);
            s1 = __builtin_amdgcn_mfma_f32_32x32x16_bf16(kB, qf2, s1, 0, 0, 0);
            kA = *(const bf16x8*)&Ks[cur][rA + co3];
            kB = *(const bf16x8*)&Ks[cur][rB + co3];
            s0 = __builtin_amdgcn_mfma_f32_32x32x16_bf16(kA, qf3, s0, 0, 0, 0);
            s1 = __builtin_amdgcn_mfma_f32_32x32x16_bf16(kB, qf3, s1, 0, 0, 0);
        }
        __builtin_amdgcn_s_setprio(0);

        float e[16], f[16];
        #pragma unroll
        for (int i = 0; i < 16; ++i) e[i] = fexp2(s0[i]);
        #pragma unroll
        for (int i = 0; i < 16; ++i) f[i] = fexp2(s1[i]);
        lsum += (((e[0]+e[1])+(e[2]+e[3])) + ((e[4]+e[5])+(e[6]+e[7])))
              + (((e[8]+e[9])+(e[10]+e[11])) + ((e[12]+e[13])+(e[14]+e[15])));
        lsum += (((f[0]+f[1])+(f[2]+f[3])) + ((f[4]+f[5])+(f[6]+f[7])))
              + (((f[8]+f[9])+(f[10]+f[11])) + ((f[12]+f[13])+(f[14]+f[15])));
        bf16x8 pf0 = pack8(e[0], e[1], e[2], e[3], e[4], e[5], e[6], e[7]);
        bf16x8 pf1 = pack8(e[8], e[9], e[10], e[11], e[12], e[13], e[14], e[15]);
        bf16x8 pf2 = pack8(f[0], f[1], f[2], f[3], f[4], f[5], f[6], f[7]);
        bf16x8 pf3 = pack8(f[8], f[9], f[10], f[11], f[12], f[13], f[14], f[15]);

        __builtin_amdgcn_s_setprio(1);
        {
            bf16x8 vA, vB;
            vA = *(const bf16x8*)&Vs[cur][rA + co0];
            vB = *(const bf16x8*)&Vs[cur][rB + co0];
            opv0 = __builtin_amdgcn_mfma_f32_32x32x16_bf16(vA, pf0, opv0, 0, 0, 0);
            opv1 = __builtin_amdgcn_mfma_f32_32x32x16_bf16(vB, pf0, opv1, 0, 0, 0);
            vA = *(const bf16x8*)&Vs[cur][rA + co1];
            vB = *(const bf16x8*)&Vs[cur][rB + co1];
            opv0 = __builtin_amdgcn_mfma_f32_32x32x16_bf16(vA, pf1, opv0, 0, 0, 0);
            opv1 = __builtin_amdgcn_mfma_f32_32x32x16_bf16(vB, pf1, opv1, 0, 0, 0);
            vA = *(const bf16x8*)&Vs[cur][rA + co2];
            vB = *(const bf16x8*)&Vs[cur][rB + co2];
            opv0 = __builtin_amdgcn_mfma_f32_32x32x16_bf16(vA, pf2, opv0, 0, 0, 0);
            opv1 = __builtin_amdgcn_mfma_f32_32x32x16_bf16(vB, pf2, opv1, 0, 0, 0);
            vA = *(const bf16x8*)&Vs[cur][rA + co3];
            vB = *(const bf16x8*)&Vs[cur][rB + co3];
            opv0 = __builtin_amdgcn_mfma_f32_32x32x16_bf16(vA, pf3, opv0, 0, 0, 0);
            opv1 = __builtin_amdgcn_mfma_f32_32x32x16_bf16(vB, pf3, opv1, 0, 0, 0);
        }
        __builtin_amdgcn_s_setprio(0);

        asm volatile("" ::: "memory");
        __builtin_amdgcn_s_barrier();
    }

    lsum += __shfl_xor(lsum, 32);

    const float inv = 1.f / lsum;
    unsigned short* ob = O + (size_t)(b * LL + q0 + l31) * HID + h * 64;
    #pragma unroll
    for (int rg = 0; rg < 4; ++rg) {
        u16x4 pkA, pkB;
        #pragma unroll
        for (int rr = 0; rr < 4; ++rr) {
            pkA[rr] = f2bf(opv0[rg * 4 + rr] * inv);
            pkB[rr] = f2bf(opv1[rg * 4 + rr] * inv);
        }
        *(u16x4*)(ob + rg * 8 + hi5 * 4)      = pkA;
        *(u16x4*)(ob + 32 + rg * 8 + hi5 * 4) = pkB;
    }
}

// ---------------- Output GEMM: 128x64 tile, BK=64, swizzled ----------------
__global__ __launch_bounds__(256) void out_gemm_kernel(
    const unsigned short* __restrict__ AOb, const unsigned short* __restrict__ Wob,
    float* __restrict__ out)
{
    __shared__ unsigned short As[128 * 64];   // 16 KB
    __shared__ unsigned short Bs[64 * 64];    // 8 KB

    const int mt = blockIdx.x;          // 0..63
    const int nt = blockIdx.y;          // 0..7
    const int mbase = mt * 128;
    const int nbase = nt * 64;

    const int tid = threadIdx.x;
    const int w = tid >> 6, lane = tid & 63;
    const int wr = w >> 1, wc = w & 1;
    const int l15 = lane & 15, koff = (lane >> 4) * 8;

    const int srow = w * 8 + (lane >> 3);
    const int ssw = ((lane & 7) * 8) ^ (((lane >> 3) & 7) * 8);
    const int rsw = (l15 & 7) * 8;
    const int ck0 = (koff +  0) ^ rsw;
    const int ck1 = (koff + 32) ^ rsw;

    f32x4 acc[4][2];
    #pragma unroll
    for (int i = 0; i < 4; ++i)
        #pragma unroll
        for (int j = 0; j < 2; ++j) acc[i][j] = (f32x4){0.f, 0.f, 0.f, 0.f};

    for (int kc = 0; kc < 512; kc += 64) {
        __syncthreads();
        #pragma unroll
        for (int j = 0; j < 4; ++j) {
            int row = j * 32 + srow;
            GLOAD_LDS16(AOb + (size_t)(mbase + row) * 512 + kc + ssw,
                        As + j * 2048 + w * 512);
        }
        #pragma unroll
        for (int c = 0; c < 2; ++c) {
            int row = c * 32 + srow;
            GLOAD_LDS16(Wob + (size_t)(nbase + row) * 512 + kc + ssw,
                        Bs + c * 2048 + w * 512);
        }
        __syncthreads();

        bf16x8 af[4][2], bf[2][2];
        #pragma unroll
        for (int mi = 0; mi < 4; ++mi) {
            int r = (wr * 64 + mi * 16 + l15) * 64;
            af[mi][0] = *(const bf16x8*)&As[r + ck0];
            af[mi][1] = *(const bf16x8*)&As[r + ck1];
        }
        #pragma unroll
        for (int ni = 0; ni < 2; ++ni) {
            int r = (wc * 32 + ni * 16 + l15) * 64;
            bf[ni][0] = *(const bf16x8*)&Bs[r + ck0];
            bf[ni][1] = *(const bf16x8*)&Bs[r + ck1];
        }
        #pragma unroll
        for (int mi = 0; mi < 4; ++mi)
            #pragma unroll
            for (int ni = 0; ni < 2; ++ni) {
                acc[mi][ni] = __builtin_amdgcn_mfma_f32_16x16x32_bf16(
                    af[mi][0], bf[ni][0], acc[mi][ni], 0, 0, 0);
                acc[mi][ni] = __builtin_amdgcn_mfma_f32_16x16x32_bf16(
                    af[mi][1], bf[ni][1], acc[mi][ni], 0, 0, 0);
            }
    }

    #pragma unroll
    for (int mi = 0; mi < 4; ++mi) {
        int m = mbase + wr * 64 + mi * 16 + (lane >> 4) * 4;
        #pragma unroll
        for (int r = 0; r < 4; ++r) {
            size_t rowbase = (size_t)(m + r) * 512 + nbase + wc * 32;
            #pragma unroll
            for (int ni = 0; ni < 2; ++ni)
                out[rowbase + ni * 16 + l15] = acc[mi][ni][r];
        }
    }
}

extern "C" void kernel_launch(void* const* d_in, const int* in_sizes, int n_in,
                              void* d_out, int out_size, void* d_ws, size_t ws_size,
                              hipStream_t stream) {
    const float* x  = (const float*)d_in[0];
    const float* Wq = (const float*)d_in[1];
    const float* Wk = (const float*)d_in[2];
    const float* Wv = (const float*)d_in[3];
    const float* Wo = (const float*)d_in[4];
    float* out = (float*)d_out;

    const size_t tblN = (size_t)LL * 32;
    const size_t qkvN = (size_t)BB * HH * LL * 64;
    const size_t wN   = (size_t)HID * HID;

    float* cos_t = (float*)d_ws;
    float* sin_t = cos_t + tblN;
    unsigned short* Qb  = (unsigned short*)(sin_t + tblN);
    unsigned short* Kb  = Qb + qkvN;
    unsigned short* Vt  = Kb + qkvN;
    unsigned short* xb  = Vt + qkvN;
    unsigned short* Wqb = xb + qkvN;
    unsigned short* Wkb = Wqb + wN;
    unsigned short* Wvb = Wkb + wN;
    unsigned short* Wob = Wvb + wN;
    unsigned short* AOb = Wob + wN;

    hipLaunchKernelGGL(convert_kernel, dim3(2048 + 512 + 128), dim3(256), 0, stream,
                       x, Wq, Wk, Wv, Wo, xb, Wqb, Wkb, Wvb, Wob, cos_t, sin_t);
    hipLaunchKernelGGL(qkv_gemm_kernel, dim3(64, 12), dim3(256), 0, stream,
                       xb, Wqb, Wkb, Wvb, cos_t, sin_t, Qb, Kb, Vt);
    hipLaunchKernelGGL(attn_kernel, dim3(512), dim3(256), 0, stream,
                       Qb, Kb, Vt, AOb);
    hipLaunchKernelGGL(out_gemm_kernel, dim3(64, 8), dim3(256), 0, stream,
                       AOb, Wob, out);
}

// Round 20
// 72.622 us; speedup vs baseline: 1.3699x; 1.0001x over previous
//
#include <hip/hip_runtime.h>
#include <math.h>

// RoPE+SDPA attention. Round 18: revert split-K (R17 failed: stale-LDS-read
// race — raw s_barrier builtin is not a compiler memory fence). attn = R16
// proven structure with HARDENED barriers (asm s_barrier + "memory" clobber).
// qkv/out/convert = R16 (best, 72.6µs).
// B=8 L=1024 H=8 Dh=64 HID=512.

#define BB 8
#define LL 1024
#define HH 8
#define DH 64
#define HID 512

typedef __bf16 bf16x8 __attribute__((ext_vector_type(8)));
typedef float f32x4 __attribute__((ext_vector_type(4)));
typedef float f32x16 __attribute__((ext_vector_type(16)));
typedef unsigned short u16x8 __attribute__((ext_vector_type(8)));
typedef unsigned short u16x4 __attribute__((ext_vector_type(4)));
typedef unsigned u32x4 __attribute__((ext_vector_type(4)));

__device__ inline unsigned short f2bf(float f) {
    union { float f; unsigned u; } v; v.f = f;
    unsigned r = v.u + 0x7fffu + ((v.u >> 16) & 1u);
    return (unsigned short)(r >> 16);
}

// single-instruction exp2 — valid for |x| well inside normal range
__device__ inline float fexp2(float x) {
    float r;
    asm("v_exp_f32 %0, %1" : "=v"(r) : "v"(x));
    return r;
}

#define GLOAD_LDS16(g, l) __builtin_amdgcn_global_load_lds( \
    (const __attribute__((address_space(1))) unsigned int*)(g), \
    (__attribute__((address_space(3))) unsigned int*)(l), 16, 0, 0)

// barrier with compiler-level memory fence (raw builtin lacks ordering)
#define SBARRIER() asm volatile("s_barrier" ::: "memory")

// T12 pack: 8 f32 C-layout P values -> one PV B-frag (cvt_pk + permlane32_swap)
__device__ inline bf16x8 pack8(float e0, float e1, float e2, float e3,
                               float e4, float e5, float e6, float e7) {
    unsigned a0, a1, a2, a3;
    asm("v_cvt_pk_bf16_f32 %0, %1, %2" : "=v"(a0) : "v"(e0), "v"(e1));
    asm("v_cvt_pk_bf16_f32 %0, %1, %2" : "=v"(a1) : "v"(e2), "v"(e3));
    asm("v_cvt_pk_bf16_f32 %0, %1, %2" : "=v"(a2) : "v"(e4), "v"(e5));
    asm("v_cvt_pk_bf16_f32 %0, %1, %2" : "=v"(a3) : "v"(e6), "v"(e7));
    asm("v_permlane32_swap_b32 %0, %1" : "+v"(a0), "+v"(a2));
    asm("v_permlane32_swap_b32 %0, %1" : "+v"(a1), "+v"(a3));
    u32x4 wv; wv[0] = a0; wv[1] = a1; wv[2] = a2; wv[3] = a3;
    return *(bf16x8*)&wv;
}

#define Z16 {0.f,0.f,0.f,0.f,0.f,0.f,0.f,0.f,0.f,0.f,0.f,0.f,0.f,0.f,0.f,0.f}

// ---------------- fp32 -> bf16 convert (x, 4 W's) + RoPE table --------------
__global__ __launch_bounds__(256) void convert_kernel(
    const float* __restrict__ x, const float* __restrict__ Wq,
    const float* __restrict__ Wk, const float* __restrict__ Wv,
    const float* __restrict__ Wo,
    unsigned short* __restrict__ xb, unsigned short* __restrict__ wqb,
    unsigned short* __restrict__ wkb, unsigned short* __restrict__ wvb,
    unsigned short* __restrict__ wob,
    float* __restrict__ cos_t, float* __restrict__ sin_t)
{
    int blk = blockIdx.x;
    if (blk >= 2560) {
        int idx = (blk - 2560) * 256 + threadIdx.x;
        int l = idx >> 5, j = idx & 31;
        float inv = exp2f(-(float)j * (13.287712379549449f / 32.0f));
        float th = (float)l * inv;
        cos_t[idx] = cosf(th);
        sin_t[idx] = sinf(th);
        return;
    }
    const float* s; unsigned short* d; int off;
    if (blk < 2048) { s = x; d = xb; off = blk; }
    else {
        int t = (blk - 2048) >> 7;
        off = (blk - 2048) & 127;
        s = (t == 0) ? Wq : (t == 1) ? Wk : (t == 2) ? Wv : Wo;
        d = (t == 0) ? wqb : (t == 1) ? wkb : (t == 2) ? wvb : wob;
    }
    size_t base = ((size_t)off * 256 + threadIdx.x) * 8;
    float4 a = *(const float4*)(s + base);
    float4 b = *(const float4*)(s + base + 4);
    u16x8 pk;
    pk[0] = f2bf(a.x); pk[1] = f2bf(a.y); pk[2] = f2bf(a.z); pk[3] = f2bf(a.w);
    pk[4] = f2bf(b.x); pk[5] = f2bf(b.y); pk[6] = f2bf(b.z); pk[7] = f2bf(b.w);
    *(u16x8*)(d + base) = pk;
}

// ---------------- QKV projection GEMM: BK=64, swizzled LDS, fused RoPE ------
__global__ __launch_bounds__(256) void qkv_gemm_kernel(
    const unsigned short* __restrict__ xb, const unsigned short* __restrict__ Wqb,
    const unsigned short* __restrict__ Wkb, const unsigned short* __restrict__ Wvb,
    const float* __restrict__ cos_t, const float* __restrict__ sin_t,
    unsigned short* __restrict__ Qb, unsigned short* __restrict__ Kb,
    unsigned short* __restrict__ Vt)
{
    __shared__ unsigned short As[128 * 64];
    __shared__ unsigned short Bs[128 * 64];

    const int mt = blockIdx.x;
    const int nt = blockIdx.y;
    const int mbase = mt * 128;
    const int mat = nt >> 2;
    const unsigned short* W = (mat == 0) ? Wqb : ((mat == 1) ? Wkb : Wvb);
    const int nW = (nt & 3) * 128;

    const int tid = threadIdx.x;
    const int w = tid >> 6, lane = tid & 63;
    const int wr = w >> 1, wc = w & 1;
    const int l15 = lane & 15, koff = (lane >> 4) * 8;

    const int srow = w * 8 + (lane >> 3);
    const int ssw = ((lane & 7) * 8) ^ (((lane >> 3) & 7) * 8);

    const int rsw = (l15 & 7) * 8;
    const int ck0 = (koff +  0) ^ rsw;
    const int ck1 = (koff + 32) ^ rsw;

    f32x4 acc[4][4];
    #pragma unroll
    for (int i = 0; i < 4; ++i)
        #pragma unroll
        for (int j = 0; j < 4; ++j) acc[i][j] = (f32x4){0.f, 0.f, 0.f, 0.f};

    for (int kc = 0; kc < 512; kc += 64) {
        __syncthreads();
        #pragma unroll
        for (int j = 0; j < 4; ++j) {
            int row = j * 32 + srow;
            GLOAD_LDS16(xb + (size_t)(mbase + row) * 512 + kc + ssw,
                        As + j * 2048 + w * 512);
            GLOAD_LDS16(W + (size_t)(nW + row) * 512 + kc + ssw,
                        Bs + j * 2048 + w * 512);
        }
        __syncthreads();

        bf16x8 af[4][2], bf[4][2];
        #pragma unroll
        for (int mi = 0; mi < 4; ++mi) {
            int r = (wr * 64 + mi * 16 + l15) * 64;
            af[mi][0] = *(const bf16x8*)&As[r + ck0];
            af[mi][1] = *(const bf16x8*)&As[r + ck1];
        }
        #pragma unroll
        for (int ni = 0; ni < 4; ++ni) {
            int r = (wc * 64 + ni * 16 + l15) * 64;
            bf[ni][0] = *(const bf16x8*)&Bs[r + ck0];
            bf[ni][1] = *(const bf16x8*)&Bs[r + ck1];
        }
        #pragma unroll
        for (int mi = 0; mi < 4; ++mi)
            #pragma unroll
            for (int ni = 0; ni < 4; ++ni) {
                acc[mi][ni] = __builtin_amdgcn_mfma_f32_16x16x32_bf16(
                    af[mi][0], bf[ni][0], acc[mi][ni], 0, 0, 0);
                acc[mi][ni] = __builtin_amdgcn_mfma_f32_16x16x32_bf16(
                    af[mi][1], bf[ni][1], acc[mi][ni], 0, 0, 0);
            }
    }

    const int h = (nt & 3) * 2 + wc;
    if (mat < 2) {
        unsigned short* D = (mat == 0) ? Qb : Kb;
        const float sc = (mat == 0) ? 0.18033688011112042f /*0.125*log2(e)*/ : 1.0f;
        #pragma unroll
        for (int mi = 0; mi < 4; ++mi) {
            int m = mbase + wr * 64 + mi * 16 + (lane >> 4) * 4;
            int b = m >> 10, l0 = m & 1023;
            #pragma unroll
            for (int r = 0; r < 4; ++r) {
                int l = l0 + r;
                float c0 = cos_t[l * 32 + l15],      s0 = sin_t[l * 32 + l15];
                float c1 = cos_t[l * 32 + 16 + l15], s1 = sin_t[l * 32 + 16 + l15];
                float a0 = acc[mi][0][r], a1 = acc[mi][1][r];
                float a2 = acc[mi][2][r], a3 = acc[mi][3][r];
                float o0 = (a0 * c0 - a2 * s0) * sc;
                float o1 = (a1 * c1 - a3 * s1) * sc;
                float o2 = (a2 * c0 + a0 * s0) * sc;
                float o3 = (a3 * c1 + a1 * s1) * sc;
                size_t rowbase = ((size_t)(b * HH + h) * LL + l) * 64;
                D[rowbase +  0 + l15] = f2bf(o0);
                D[rowbase + 16 + l15] = f2bf(o1);
                D[rowbase + 32 + l15] = f2bf(o2);
                D[rowbase + 48 + l15] = f2bf(o3);
            }
        }
    } else {
        #pragma unroll
        for (int mi = 0; mi < 4; ++mi) {
            int m = mbase + wr * 64 + mi * 16 + (lane >> 4) * 4;
            int b = m >> 10, l0 = m & 1023;
            #pragma unroll
            for (int ni = 0; ni < 4; ++ni) {
                int d = ni * 16 + l15;
                u16x4 pk;
                #pragma unroll
                for (int r = 0; r < 4; ++r) pk[r] = f2bf(acc[mi][ni][r]);
                *(u16x4*)(Vt + ((size_t)(b * HH + h) * 64 + d) * LL + l0) = pk;
            }
        }
    }
}

// ---------------- Flash attention: R12/R16 structure, hardened barriers -----
__global__ __launch_bounds__(256) void attn_kernel(
    const unsigned short* __restrict__ Q, const unsigned short* __restrict__ K,
    const unsigned short* __restrict__ Vt, unsigned short* __restrict__ O)
{
    __shared__ unsigned short Ks[2][64 * 64];    // 16 KB
    __shared__ unsigned short Vs[2][64 * 64];    // 16 KB

    const int wgid = blockIdx.x;    // 0..511
    const int xcd = wgid & 7;
    const int j = wgid >> 3;        // 0..63
    const int bh = xcd * 8 + (j >> 3);
    const int qt = j & 7;
    const int b = bh >> 3, h = bh & 7;
    const int tid = threadIdx.x;
    const int w = tid >> 6;         // 0..3
    const int lane = tid & 63;
    const int l31 = lane & 31;
    const int hi5 = lane >> 5;

    const unsigned short* Qp = Q + (size_t)bh * LL * 64;
    const unsigned short* Kp = K + (size_t)bh * LL * 64;
    const unsigned short* Vp = Vt + (size_t)bh * 64 * LL;

    const int sr0 = w * 8 + (lane >> 3);
    const int sr1 = 32 + w * 8 + (lane >> 3);
    const int scsw = ((lane & 7) * 8) ^ (((lane >> 3) & 7) * 8);
    const int sd0 = w * 512;
    const int sd1 = 2048 + w * 512;

    const int q0 = qt * 128 + w * 32;

    bf16x8 qf0 = *(const bf16x8*)(Qp + (size_t)(q0 + l31) * 64 +  0 + hi5 * 8);
    bf16x8 qf1 = *(const bf16x8*)(Qp + (size_t)(q0 + l31) * 64 + 16 + hi5 * 8);
    bf16x8 qf2 = *(const bf16x8*)(Qp + (size_t)(q0 + l31) * 64 + 32 + hi5 * 8);
    bf16x8 qf3 = *(const bf16x8*)(Qp + (size_t)(q0 + l31) * 64 + 48 + hi5 * 8);

    const int swz = (l31 & 7) * 8;
    const int co0 = ( 0 + hi5 * 8) ^ swz;
    const int co1 = (16 + hi5 * 8) ^ swz;
    const int co2 = (32 + hi5 * 8) ^ swz;
    const int co3 = (48 + hi5 * 8) ^ swz;
    const int rA = l31 * 64;
    const int rB = (32 + l31) * 64;

    float lsum = 0.f;
    f32x16 opv0 = Z16, opv1 = Z16;

    GLOAD_LDS16(Kp + (size_t)sr0 * 64 + scsw, &Ks[0][sd0]);
    GLOAD_LDS16(Kp + (size_t)sr1 * 64 + scsw, &Ks[0][sd1]);
    GLOAD_LDS16(Vp + (size_t)sr0 * LL + scsw, &Vs[0][sd0]);
    GLOAD_LDS16(Vp + (size_t)sr1 * LL + scsw, &Vs[0][sd1]);
    __syncthreads();

    #pragma unroll 2
    for (int kt = 0; kt < 16; ++kt) {
        const int cur = kt & 1, nxt = cur ^ 1;
        const int kbase = kt * 64;

        if (kt < 15) {
            GLOAD_LDS16(Kp + (size_t)(kbase + 64 + sr0) * 64 + scsw, &Ks[nxt][sd0]);
            GLOAD_LDS16(Kp + (size_t)(kbase + 64 + sr1) * 64 + scsw, &Ks[nxt][sd1]);
            GLOAD_LDS16(Vp + (size_t)sr0 * LL + kbase + 64 + scsw, &Vs[nxt][sd0]);
            GLOAD_LDS16(Vp + (size_t)sr1 * LL + kbase + 64 + scsw, &Vs[nxt][sd1]);
            asm volatile("s_waitcnt vmcnt(4)" ::: "memory");
        } else {
            asm volatile("s_waitcnt vmcnt(0)" ::: "memory");
        }
        SBARRIER();

        f32x16 s0 = Z16, s1 = Z16;
        __builtin_amdgcn_s_setprio(1);
        {
            bf16x8 kA, kB;
            kA = *(const bf16x8*)&Ks[cur][rA + co0];
            kB = *(const bf16x8*)&Ks[cur][rB + co0];
            s0 = __builtin_amdgcn_mfma_f32_32x32x16_bf16(kA, qf0, s0, 0, 0, 0);
            s1 = __builtin_amdgcn_mfma_f32_32x32x16_bf16(kB, qf0, s1, 0, 0, 0);
            kA = *(const bf16x8*)&Ks[cur][rA + co1];
            kB = *(const bf16x8*)&Ks[cur][rB + co1];
            s0 = __builtin_amdgcn_mfma_f32_32x32x16_bf16(kA, qf1, s0, 0, 0, 0);
            s1 = __builtin_amdgcn_mfma_f32_32x32x16_bf16(kB, qf1, s1, 0, 0, 0);
            kA = *(const bf16x8*)&Ks[cur][rA + co2];
            kB = *(const bf16x8*)&Ks[cur][rB + co2];
            s0 = __builtin_amdgcn_mfma_f32_32x32x16_bf16(kA, qf2, s0, 0, 0, 0);
            s1 = __builtin_amdgcn_mfma_f32_32x32x16_bf16(kB, qf2, s1, 0, 0, 0);
            kA = *(const bf16x8*)&Ks[cur][rA + co3];
            kB = *(const bf16x8*)&Ks[cur][rB + co3];
            s0 = __builtin_amdgcn_mfma_f32_32x32x16_bf16(kA, qf3, s0, 0, 0, 0);
            s1 = __builtin_amdgcn_mfma_f32_32x32x16_bf16(kB, qf3, s1, 0, 0, 0);
        }
        __builtin_amdgcn_s_setprio(0);

        float e[16], f[16];
        #pragma unroll
        for (int i = 0; i < 16; ++i) e[i] = fexp2(s0[i]);
        #pragma unroll
        for (int i = 0; i < 16; ++i) f[i] = fexp2(s1[i]);
        lsum += (((e[0]+e[1])+(e[2]+e[3])) + ((e[4]+e[5])+(e[6]+e[7])))
              + (((e[8]+e[9])+(e[10]+e[11])) + ((e[12]+e[13])+(e[14]+e[15])));
        lsum += (((f[0]+f[1])+(f[2]+f[3])) + ((f[4]+f[5])+(f[6]+f[7])))
              + (((f[8]+f[9])+(f[10]+f[11])) + ((f[12]+f[13])+(f[14]+f[15])));
        bf16x8 pf0 = pack8(e[0], e[1], e[2], e[3], e[4], e[5], e[6], e[7]);
        bf16x8 pf1 = pack8(e[8], e[9], e[10], e[11], e[12], e[13], e[14], e[15]);
        bf16x8 pf2 = pack8(f[0], f[1], f[2], f[3], f[4], f[5], f[6], f[7]);
        bf16x8 pf3 = pack8(f[8], f[9], f[10], f[11], f[12], f[13], f[14], f[15]);

        __builtin_amdgcn_s_setprio(1);
        {
            bf16x8 vA, vB;
            vA = *(const bf16x8*)&Vs[cur][rA + co0];
            vB = *(const bf16x8*)&Vs[cur][rB + co0];
            opv0 = __builtin_amdgcn_mfma_f32_32x32x16_bf16(vA, pf0, opv0, 0, 0, 0);
            opv1 = __builtin_amdgcn_mfma_f32_32x32x16_bf16(vB, pf0, opv1, 0, 0, 0);
            vA = *(const bf16x8*)&Vs[cur][rA + co1];
            vB = *(const bf16x8*)&Vs[cur][rB + co1];
            opv0 = __builtin_amdgcn_mfma_f32_32x32x16_bf16(vA, pf1, opv0, 0, 0, 0);
            opv1 = __builtin_amdgcn_mfma_f32_32x32x16_bf16(vB, pf1, opv1, 0, 0, 0);
            vA = *(const bf16x8*)&Vs[cur][rA + co2];
            vB = *(const bf16x8*)&Vs[cur][rB + co2];
            opv0 = __builtin_amdgcn_mfma_f32_32x32x16_bf16(vA, pf2, opv0, 0, 0, 0);
            opv1 = __builtin_amdgcn_mfma_f32_32x32x16_bf16(vB, pf2, opv1, 0, 0, 0);
            vA = *(const bf16x8*)&Vs[cur][rA + co3];
            vB = *(const bf16x8*)&Vs[cur][rB + co3];
            opv0 = __builtin_amdgcn_mfma_f32_32x32x16_bf16(vA, pf3, opv0, 0, 0, 0);
            opv1 = __builtin_amdgcn_mfma_f32_32x32x16_bf16(vB, pf3, opv1, 0, 0, 0);
        }
        __builtin_amdgcn_s_setprio(0);

        SBARRIER();
    }

    lsum += __shfl_xor(lsum, 32);

    const float inv = 1.f / lsum;
    unsigned short* ob = O + (size_t)(b * LL + q0 + l31) * HID + h * 64;
    #pragma unroll
    for (int rg = 0; rg < 4; ++rg) {
        u16x4 pkA, pkB;
        #pragma unroll
        for (int rr = 0; rr < 4; ++rr) {
            pkA[rr] = f2bf(opv0[rg * 4 + rr] * inv);
            pkB[rr] = f2bf(opv1[rg * 4 + rr] * inv);
        }
        *(u16x4*)(ob + rg * 8 + hi5 * 4)      = pkA;
        *(u16x4*)(ob + 32 + rg * 8 + hi5 * 4) = pkB;
    }
}

// ---------------- Output GEMM: 128x64 tile, BK=64, swizzled ----------------
__global__ __launch_bounds__(256) void out_gemm_kernel(
    const unsigned short* __restrict__ AOb, const unsigned short* __restrict__ Wob,
    float* __restrict__ out)
{
    __shared__ unsigned short As[128 * 64];   // 16 KB
    __shared__ unsigned short Bs[64 * 64];    // 8 KB

    const int mt = blockIdx.x;          // 0..63
    const int nt = blockIdx.y;          // 0..7
    const int mbase = mt * 128;
    const int nbase = nt * 64;

    const int tid = threadIdx.x;
    const int w = tid >> 6, lane = tid & 63;
    const int wr = w >> 1, wc = w & 1;
    const int l15 = lane & 15, koff = (lane >> 4) * 8;

    const int srow = w * 8 + (lane >> 3);
    const int ssw = ((lane & 7) * 8) ^ (((lane >> 3) & 7) * 8);
    const int rsw = (l15 & 7) * 8;
    const int ck0 = (koff +  0) ^ rsw;
    const int ck1 = (koff + 32) ^ rsw;

    f32x4 acc[4][2];
    #pragma unroll
    for (int i = 0; i < 4; ++i)
        #pragma unroll
        for (int j = 0; j < 2; ++j) acc[i][j] = (f32x4){0.f, 0.f, 0.f, 0.f};

    for (int kc = 0; kc < 512; kc += 64) {
        __syncthreads();
        #pragma unroll
        for (int j = 0; j < 4; ++j) {
            int row = j * 32 + srow;
            GLOAD_LDS16(AOb + (size_t)(mbase + row) * 512 + kc + ssw,
                        As + j * 2048 + w * 512);
        }
        #pragma unroll
        for (int c = 0; c < 2; ++c) {
            int row = c * 32 + srow;
            GLOAD_LDS16(Wob + (size_t)(nbase + row) * 512 + kc + ssw,
                        Bs + c * 2048 + w * 512);
        }
        __syncthreads();

        bf16x8 af[4][2], bf[2][2];
        #pragma unroll
        for (int mi = 0; mi < 4; ++mi) {
            int r = (wr * 64 + mi * 16 + l15) * 64;
            af[mi][0] = *(const bf16x8*)&As[r + ck0];
            af[mi][1] = *(const bf16x8*)&As[r + ck1];
        }
        #pragma unroll
        for (int ni = 0; ni < 2; ++ni) {
            int r = (wc * 32 + ni * 16 + l15) * 64;
            bf[ni][0] = *(const bf16x8*)&Bs[r + ck0];
            bf[ni][1] = *(const bf16x8*)&Bs[r + ck1];
        }
        #pragma unroll
        for (int mi = 0; mi < 4; ++mi)
            #pragma unroll
            for (int ni = 0; ni < 2; ++ni) {
                acc[mi][ni] = __builtin_amdgcn_mfma_f32_16x16x32_bf16(
                    af[mi][0], bf[ni][0], acc[mi][ni], 0, 0, 0);
                acc[mi][ni] = __builtin_amdgcn_mfma_f32_16x16x32_bf16(
                    af[mi][1], bf[ni][1], acc[mi][ni], 0, 0, 0);
            }
    }

    #pragma unroll
    for (int mi = 0; mi < 4; ++mi) {
        int m = mbase + wr * 64 + mi * 16 + (lane >> 4) * 4;
        #pragma unroll
        for (int r = 0; r < 4; ++r) {
            size_t rowbase = (size_t)(m + r) * 512 + nbase + wc * 32;
            #pragma unroll
            for (int ni = 0; ni < 2; ++ni)
                out[rowbase + ni * 16 + l15] = acc[mi][ni][r];
        }
    }
}

extern "C" void kernel_launch(void* const* d_in, const int* in_sizes, int n_in,
                              void* d_out, int out_size, void* d_ws, size_t ws_size,
                              hipStream_t stream) {
    const float* x  = (const float*)d_in[0];
    const float* Wq = (const float*)d_in[1];
    const float* Wk = (const float*)d_in[2];
    const float* Wv = (const float*)d_in[3];
    const float* Wo = (const float*)d_in[4];
    float* out = (float*)d_out;

    const size_t tblN = (size_t)LL * 32;
    const size_t qkvN = (size_t)BB * HH * LL * 64;
    const size_t wN   = (size_t)HID * HID;

    float* cos_t = (float*)d_ws;
    float* sin_t = cos_t + tblN;
    unsigned short* Qb  = (unsigned short*)(sin_t + tblN);
    unsigned short* Kb  = Qb + qkvN;
    unsigned short* Vt  = Kb + qkvN;
    unsigned short* xb  = Vt + qkvN;
    unsigned short* Wqb = xb + qkvN;
    unsigned short* Wkb = Wqb + wN;
    unsigned short* Wvb = Wkb + wN;
    unsigned short* Wob = Wvb + wN;
    unsigned short* AOb = Wob + wN;

    hipLaunchKernelGGL(convert_kernel, dim3(2048 + 512 + 128), dim3(256), 0, stream,
                       x, Wq, Wk, Wv, Wo, xb, Wqb, Wkb, Wvb, Wob, cos_t, sin_t);
    hipLaunchKernelGGL(qkv_gemm_kernel, dim3(64, 12), dim3(256), 0, stream,
                       xb, Wqb, Wkb, Wvb, cos_t, sin_t, Qb, Kb, Vt);
    hipLaunchKernelGGL(attn_kernel, dim3(512), dim3(256), 0, stream,
                       Qb, Kb, Vt, AOb);
    hipLaunchKernelGGL(out_gemm_kernel, dim3(64, 8), dim3(256), 0, stream,
                       AOb, Wob, out);
}